// Round 3
// baseline (806.766 us; speedup 1.0000x reference)
//
#include <hip/hip_runtime.h>
#include <hip/hip_bf16.h>

constexpr int B  = 16;
constexpr int C  = 128;
constexpr int H  = 128;
constexpr int W  = 128;
constexpr int CO = 256;
constexpr int HO = 64;
constexpr int WO = 64;

#define EPSV   1e-8f
#define SLOPE  0.2f

typedef short bf16x8 __attribute__((ext_vector_type(8)));
typedef float f32x4  __attribute__((ext_vector_type(4)));

__device__ __forceinline__ short f2bs(float v) {
    __hip_bfloat16 h = __float2bfloat16(v);
    return *(short*)&h;
}
__device__ __forceinline__ float bs2f(short s) {
    __hip_bfloat16 h = *(__hip_bfloat16*)&s;
    return __bfloat162float(h);
}

// ---------------------------------------------------------------------------
// demod: d[conv][b][o] = rsqrt(sum_{i,k}(w[o,i,k]*(s[b,i]+1))^2 + eps)
// ---------------------------------------------------------------------------
__global__ __launch_bounds__(128) void demod_kernel(
    const float* __restrict__ w1, const float* __restrict__ w2,
    const float* __restrict__ s1, const float* __restrict__ s2,
    float* __restrict__ d)
{
    int bid  = blockIdx.x;          // conv*2048 + b*128 + o
    int conv = bid >> 11;
    int b    = (bid >> 7) & 15;
    int o    = bid & 127;
    const float* w = conv ? w2 : w1;
    const float* s = conv ? s2 : s1;
    int i = threadIdx.x;
    float sv = s[b * C + i] + 1.0f;
    const float* wp = w + (o * C + i) * 9;
    float sum = 0.f;
    #pragma unroll
    for (int k = 0; k < 9; ++k) { float t = wp[k] * sv; sum += t * t; }
    #pragma unroll
    for (int off = 32; off; off >>= 1) sum += __shfl_down(sum, off);
    __shared__ float red[2];
    if ((threadIdx.x & 63) == 0) red[threadIdx.x >> 6] = sum;
    __syncthreads();
    if (threadIdx.x == 0) d[bid] = rsqrtf(red[0] + red[1] + EPSV);
}

// ---------------------------------------------------------------------------
// expand -> wave-coalesced B-fragment tiling:
// wm[cb][tap][ocT=oc>>4][icC=ic>>5][(oc&15)*32 + (ic&31)]   (bf16)
// one fragment (tap,ocT,icC) = 512 elems = 1KB contiguous; lane reads
// l15*32 + q*8 -> perfectly coalesced per wave.
// ---------------------------------------------------------------------------
__global__ __launch_bounds__(256) void expand_kernel(
    const float* __restrict__ w1, const float* __restrict__ w2,
    const float* __restrict__ s1, const float* __restrict__ s2,
    const float* __restrict__ d, short* __restrict__ wm)
{
    int idx = blockIdx.x * 256 + threadIdx.x;
    int ic  = idx & 127;
    int oc  = (idx >> 7) & 127;
    int t   = idx >> 14;            // cb*9+tap, < 288
    int tap = t % 9;
    int cb  = t / 9;                // conv*16+b
    int b   = cb & 15;
    int conv= cb >> 4;
    const float* w = conv ? w2 : w1;
    const float* s = conv ? s2 : s1;
    float v = w[(oc * C + ic) * 9 + tap] * (s[b * C + ic] + 1.0f)
            * d[(conv * B + b) * C + oc];
    int dst = cb * 147456
            + ((tap * 8 + (oc >> 4)) * 4 + (ic >> 5)) * 512
            + (oc & 15) * 32 + (ic & 31);
    wm[dst] = f2bs(v);
}

// ---------------------------------------------------------------------------
// dwexpand: dwm[tap][ocT=oc>>4 (16)][icC=ic>>5 (4)][(oc&15)*32+(ic&31)]
// ---------------------------------------------------------------------------
__global__ __launch_bounds__(256) void dwexpand_kernel(
    const float* __restrict__ dw, short* __restrict__ dwm)
{
    int idx = blockIdx.x * 256 + threadIdx.x;   // 16*256*128 = 524288
    int ic  = idx & 127;
    int oc  = (idx >> 7) & 255;
    int tap = idx >> 15;
    int dst = ((tap * 16 + (oc >> 4)) * 4 + (ic >> 5)) * 512
            + (oc & 15) * 32 + (ic & 31);
    dwm[dst] = f2bs(dw[(oc * C + ic) * 16 + tap]);
}

// ---------------------------------------------------------------------------
// nchw(f32) -> nhwc(bf16) transpose of features.
// ---------------------------------------------------------------------------
__global__ __launch_bounds__(256) void nchw2nhwc_kernel(
    const float* __restrict__ in, short* __restrict__ out)
{
    __shared__ short s[128 * 136];
    int bid = blockIdx.x;                   // b*128 + h
    int h = bid & 127, b = bid >> 7;
    int tid = threadIdx.x;
    for (int i = tid; i < 128 * 32; i += 256) {
        int w4 = i & 31, ic = i >> 5;
        float4 v = *(const float4*)&in[((b * C + ic) * H + h) * W + w4 * 4];
        s[(w4 * 4 + 0) * 136 + ic] = f2bs(v.x);
        s[(w4 * 4 + 1) * 136 + ic] = f2bs(v.y);
        s[(w4 * 4 + 2) * 136 + ic] = f2bs(v.z);
        s[(w4 * 4 + 3) * 136 + ic] = f2bs(v.w);
    }
    __syncthreads();
    for (int i = tid; i < 128 * 16; i += 256) {
        int icg = i & 15, w = i >> 4;
        *(uint4*)&out[((b * H + h) * W + w) * C + icg * 8] =
            *(uint4*)&s[w * 136 + icg * 8];
    }
}

// ---------------------------------------------------------------------------
// conv3x3 MFMA implicit GEMM, register-double-buffered K pipeline.
// block tile: 128 px (8h x 16w) x 128 oc; wave: 64 px x 64 oc.
// K steps: 9 taps x 4 ic-chunks = 36; prefetch step s+1 during MFMAs of s.
// ---------------------------------------------------------------------------
__global__ __launch_bounds__(256, 3) void conv3x3_mfma(
    const short* __restrict__ in, const short* __restrict__ wmc,
    const short* __restrict__ res, short* __restrict__ out)
{
    __shared__ short sIn[10 * 18 * 136];   // 48,960 B

    int bid = blockIdx.x;
    int wt = bid & 7, ht = (bid >> 3) & 15, b = bid >> 7;
    int w0 = wt * 16, h0 = ht * 8;
    int tid  = threadIdx.x;
    int lane = tid & 63, wv = tid >> 6;
    int q = lane >> 4, l15 = lane & 15;
    int wr = wv & 1;       // row half
    int wc = wv >> 1;      // oc half

    for (int i = tid; i < 10 * 18 * 16; i += 256) {
        int icg = i & 15;
        int t = i >> 4;
        int wl = t % 18, hl = t / 18;
        int gh = h0 - 1 + hl, gw = w0 - 1 + wl;
        uint4 v = make_uint4(0u, 0u, 0u, 0u);
        if ((unsigned)gh < (unsigned)H && (unsigned)gw < (unsigned)W)
            v = *(const uint4*)&in[((b * H + gh) * W + gw) * C + icg * 8];
        *(uint4*)&sIn[(hl * 18 + wl) * 136 + icg * 8] = v;
    }
    __syncthreads();

    const short* wb = wmc + b * 147456;

    f32x4 acc[4][4];
    #pragma unroll
    for (int mt = 0; mt < 4; ++mt)
        #pragma unroll
        for (int nt = 0; nt < 4; ++nt)
            acc[mt][nt] = (f32x4){0.f, 0.f, 0.f, 0.f};

    bf16x8 af[2][4], bf[2][4];

    // prologue: (tap=0 -> dh=0,dw=0, c=0) into parity 0
    #pragma unroll
    for (int mt = 0; mt < 4; ++mt)
        af[0][mt] = *(const bf16x8*)&sIn[((wr * 4 + mt) * 18 + l15) * 136 + q * 8];
    #pragma unroll
    for (int nt = 0; nt < 4; ++nt)
        bf[0][nt] = *(const bf16x8*)&wb[((0 * 8 + wc * 4 + nt) * 4 + 0) * 512
                                        + l15 * 32 + q * 8];

    #pragma unroll 1
    for (int tap = 0; tap < 9; ++tap) {
        int dh  = tap / 3,  dwd = tap - dh * 3;
        int tapn = (tap + 1 < 9) ? tap + 1 : tap;   // dummy prefetch on last
        int dhn = tapn / 3, dwn = tapn - dhn * 3;
        #pragma unroll
        for (int c = 0; c < 4; ++c) {
            int p  = c & 1, pn = p ^ 1;
            int cn = (c + 1) & 3;
            int tE  = (c == 3) ? tapn : tap;
            int dhE = (c == 3) ? dhn : dh;
            int dwE = (c == 3) ? dwn : dwd;
            // prefetch step s+1
            #pragma unroll
            for (int mt = 0; mt < 4; ++mt)
                af[pn][mt] = *(const bf16x8*)&sIn[((wr * 4 + mt + dhE) * 18 + l15 + dwE) * 136
                                                  + cn * 32 + q * 8];
            #pragma unroll
            for (int nt = 0; nt < 4; ++nt)
                bf[pn][nt] = *(const bf16x8*)&wb[((tE * 8 + wc * 4 + nt) * 4 + cn) * 512
                                                 + l15 * 32 + q * 8];
            // compute step s
            #pragma unroll
            for (int mt = 0; mt < 4; ++mt)
                #pragma unroll
                for (int nt = 0; nt < 4; ++nt)
                    acc[mt][nt] = __builtin_amdgcn_mfma_f32_16x16x32_bf16(
                        af[p][mt], bf[p][nt], acc[mt][nt], 0, 0, 0);
        }
    }

    bool has_res = (res != nullptr);
    #pragma unroll
    for (int mt = 0; mt < 4; ++mt) {
        int h = h0 + wr * 4 + mt;
        #pragma unroll
        for (int nt = 0; nt < 4; ++nt) {
            int oc = wc * 64 + nt * 16 + l15;
            #pragma unroll
            for (int reg = 0; reg < 4; ++reg) {
                int w = w0 + q * 4 + reg;
                int idx = ((b * H + h) * W + w) * C + oc;
                float v = acc[mt][nt][reg];
                if (has_res) v += bs2f(res[idx]);
                v = v >= 0.f ? v : SLOPE * v;
                out[idx] = f2bs(v);
            }
        }
    }
}

// ---------------------------------------------------------------------------
// downconv MFMA, round-3 restructure for occupancy + pipelining.
//  - Round-2 evidence: MFMA pipe ~4.5% busy, occupancy 8 waves/CU (LDS 54.7KB
//    x2 + 192 regs/wave both cap at 2 blocks/CU), 8 barriers/block with a
//    serial stage phase per chunk.  Latency-bound on parallelism, not on
//    per-instruction latency (distance-3 A-ring only bought 10%).
//  - New: block = 4oh x 16ow x 256oc (grid still 1024, no ot split -> input
//    staged once). Per wave: 4 ocT x 4 pxT 16x16 tiles (acc 64 AGPR), same
//    16 MFMA : 4A+4B ratio as before.
//  - LDS: [icg(4)][unit(340)][8 shorts] per buffer = 21,760 B; unit =
//    (hl*2+par)*17 + half (deinterleaved stride-2).  16B-aligned r/w, <=2-way
//    banks. Double-buffered: 43,520 B total -> 3 blocks/CU.
//  - One barrier per chunk: stage chunk c+1 into buf[c^1] after chunk c's
//    taps (buf[c^1] was last READ in chunk c-1, protected by that barrier).
//  - A-ring back to distance-1 (af[2]) to fit <=168 regs/wave for 3/SIMD.
// ---------------------------------------------------------------------------
__global__ __launch_bounds__(256, 3) void downconv_mfma(
    const short* __restrict__ in, const short* __restrict__ dwm,
    const float* __restrict__ db, float* __restrict__ out)
{
    __shared__ short sIn[2][4 * 340 * 8];   // 2 x 21,760 B = 43,520 B

    int bid = blockIdx.x;
    int wt = bid & 3;   bid >>= 2;   // ow tile (16 wide)
    int ht = bid & 15;  bid >>= 4;   // oh tile (4 tall)
    int b  = bid;
    int ow0 = wt * 16, oh0 = ht * 4;

    int tid  = threadIdx.x;
    int lane = tid & 63, wv = tid >> 6;
    int q = lane >> 4, l15 = lane & 15;

    f32x4 acc[4][4];
    #pragma unroll
    for (int mt = 0; mt < 4; ++mt)
        #pragma unroll
        for (int nt = 0; nt < 4; ++nt)
            acc[mt][nt] = (f32x4){0.f, 0.f, 0.f, 0.f};

    int ocTb = wv * 4;   // this wave's oc-tile base (16-oc units, 0..15)

    // ---- stage ic-chunk 0 -> buf 0 ----
    // pixels: hl in [0,10), wl in [0,34); unit = (hl*2 + (wl&1))*17 + (wl>>1)
    #pragma unroll
    for (int j = 0; j < 6; ++j) {
        int i = tid + j * 256;
        if (i < 10 * 34 * 4) {
            int icg = i & 3;
            int t = i >> 2;
            int wl = t % 34, hl = t / 34;
            int gh = 2 * oh0 - 1 + hl, gw = 2 * ow0 - 1 + wl;
            uint4 v = make_uint4(0u, 0u, 0u, 0u);
            if ((unsigned)gh < (unsigned)H && (unsigned)gw < (unsigned)W)
                v = *(const uint4*)&in[((b * H + gh) * W + gw) * C + icg * 8];
            int u = (hl * 2 + (wl & 1)) * 17 + (wl >> 1);
            *(uint4*)&sIn[0][(icg * 340 + u) * 8] = v;
        }
    }

    bf16x8 af[2][4];   // A (weights) double-buffer, distance-1
    bf16x8 bf[2][4];   // B (pixels)  double-buffer, distance-1

    // A prologue: flattened step 0 (c=0, tap=0)
    #pragma unroll
    for (int mt = 0; mt < 4; ++mt)
        af[0][mt] = *(const bf16x8*)&dwm[((0 * 16 + ocTb + mt) * 4 + 0) * 512
                                         + l15 * 32 + q * 8];

    __syncthreads();

    #pragma unroll 1
    for (int c = 0; c < 4; ++c) {
        const short* sb = sIn[c & 1];

        // B prologue: tap 0 (dh=0, dw=0): hl=2*nt, par=0, half=l15
        #pragma unroll
        for (int nt = 0; nt < 4; ++nt)
            bf[0][nt] = *(const bf16x8*)&sb[(q * 340 + (4 * nt) * 17 + l15) * 8];

        #pragma unroll
        for (int tap = 0; tap < 16; ++tap) {
            // A prefetch: flattened step +1 (crosses the c boundary)
            {
                int pc = (tap == 15) ? ((c < 3) ? c + 1 : 3) : c;
                int pt = (tap == 15) ? ((c < 3) ? 0 : 15) : tap + 1;
                #pragma unroll
                for (int mt = 0; mt < 4; ++mt)
                    af[(tap + 1) & 1][mt] =
                        *(const bf16x8*)&dwm[((pt * 16 + ocTb + mt) * 4 + pc) * 512
                                             + l15 * 32 + q * 8];
            }
            // B prefetch: tap+1 (dummy on last)
            {
                int tapn = (tap + 1 < 16) ? tap + 1 : tap;
                int dhn = tapn >> 2, dwn = tapn & 3;
                #pragma unroll
                for (int nt = 0; nt < 4; ++nt) {
                    int u = ((2 * nt + dhn) * 2 + (dwn & 1)) * 17 + l15 + (dwn >> 1);
                    bf[(tap + 1) & 1][nt] = *(const bf16x8*)&sb[(q * 340 + u) * 8];
                }
            }
            // compute tap
            #pragma unroll
            for (int mt = 0; mt < 4; ++mt)
                #pragma unroll
                for (int nt = 0; nt < 4; ++nt)
                    acc[mt][nt] = __builtin_amdgcn_mfma_f32_16x16x32_bf16(
                        af[tap & 1][mt], bf[tap & 1][nt], acc[mt][nt], 0, 0, 0);
        }

        // stage chunk c+1 -> buf[(c+1)&1]; safe: that buffer was last read
        // in chunk c-1, all readers passed the barrier at end of chunk c-1.
        if (c < 3) {
            short* sw = sIn[(c + 1) & 1];
            #pragma unroll
            for (int j = 0; j < 6; ++j) {
                int i = tid + j * 256;
                if (i < 10 * 34 * 4) {
                    int icg = i & 3;
                    int t = i >> 2;
                    int wl = t % 34, hl = t / 34;
                    int gh = 2 * oh0 - 1 + hl, gw = 2 * ow0 - 1 + wl;
                    uint4 v = make_uint4(0u, 0u, 0u, 0u);
                    if ((unsigned)gh < (unsigned)H && (unsigned)gw < (unsigned)W)
                        v = *(const uint4*)&in[((b * H + gh) * W + gw) * C
                                               + (c + 1) * 32 + icg * 8];
                    int u = (hl * 2 + (wl & 1)) * 17 + (wl >> 1);
                    *(uint4*)&sIn[(c + 1) & 1][(icg * 340 + u) * 8] = v;
                }
            }
            (void)sw;
        }
        __syncthreads();
    }

    #pragma unroll
    for (int mt = 0; mt < 4; ++mt) {
        #pragma unroll
        for (int reg = 0; reg < 4; ++reg) {
            int oc = wv * 64 + mt * 16 + q * 4 + reg;
            float bias = db[oc];
            #pragma unroll
            for (int nt = 0; nt < 4; ++nt) {
                int oh = oh0 + nt;
                int ow = ow0 + l15;
                out[((b * CO + oc) * HO + oh) * WO + ow] = acc[mt][nt][reg] + bias;
            }
        }
    }
}

// ---------------------------------------------------------------------------
extern "C" void kernel_launch(void* const* d_in, const int* in_sizes, int n_in,
                              void* d_out, int out_size, void* d_ws, size_t ws_size,
                              hipStream_t stream) {
    const float* features = (const float*)d_in[0];
    const float* sm1      = (const float*)d_in[1];   // style_mean1 -> s1
    const float* ss1      = (const float*)d_in[2];   // style_std1  -> s2 (per reference)
    const float* w1       = (const float*)d_in[6];
    const float* w2       = (const float*)d_in[7];
    const float* dw       = (const float*)d_in[8];
    const float* db       = (const float*)d_in[9];
    float* out = (float*)d_out;

    char* ws = (char*)d_ws;
    short* x1  = (short*)ws;                              // 67,108,864 B
    short* x2  = (short*)(ws + 67108864);                 // 67,108,864 B (also fx)
    short* wm  = (short*)(ws + 134217728);                // 9,437,184 B
    short* dwm = (short*)(ws + 143654912);                // 1,048,576 B
    float* dv  = (float*)(ws + 144703488);                // 16,384 B

    demod_kernel    <<<4096, 128, 0, stream>>>(w1, w2, sm1, ss1, dv);
    expand_kernel   <<<18432, 256, 0, stream>>>(w1, w2, sm1, ss1, dv, wm);
    dwexpand_kernel <<<2048, 256, 0, stream>>>(dw, dwm);
    nchw2nhwc_kernel<<<2048, 256, 0, stream>>>(features, x2);
    conv3x3_mfma    <<<2048, 256, 0, stream>>>(x2, wm, nullptr, x1);
    conv3x3_mfma    <<<2048, 256, 0, stream>>>(x1, wm + 16 * 147456, x1, x2);
    // downconv: grid = 4 ow-tiles x 16 oh-tiles x 16 b = 1024 blocks, 256 oc each
    downconv_mfma   <<<1024, 256, 0, stream>>>(x2, dwm, db, out);
}

// Round 4
// 544.105 us; speedup vs baseline: 1.4827x; 1.4827x over previous
//
#include <hip/hip_runtime.h>
#include <hip/hip_bf16.h>

constexpr int B  = 16;
constexpr int C  = 128;
constexpr int H  = 128;
constexpr int W  = 128;
constexpr int CO = 256;
constexpr int HO = 64;
constexpr int WO = 64;

#define EPSV   1e-8f
#define SLOPE  0.2f

typedef short bf16x8 __attribute__((ext_vector_type(8)));
typedef float f32x4  __attribute__((ext_vector_type(4)));

__device__ __forceinline__ short f2bs(float v) {
    __hip_bfloat16 h = __float2bfloat16(v);
    return *(short*)&h;
}
__device__ __forceinline__ float bs2f(short s) {
    __hip_bfloat16 h = *(__hip_bfloat16*)&s;
    return __bfloat162float(h);
}

// ---------------------------------------------------------------------------
// demod: d[conv][b][o] = rsqrt(sum_{i,k}(w[o,i,k]*(s[b,i]+1))^2 + eps)
// ---------------------------------------------------------------------------
__global__ __launch_bounds__(128) void demod_kernel(
    const float* __restrict__ w1, const float* __restrict__ w2,
    const float* __restrict__ s1, const float* __restrict__ s2,
    float* __restrict__ d)
{
    int bid  = blockIdx.x;          // conv*2048 + b*128 + o
    int conv = bid >> 11;
    int b    = (bid >> 7) & 15;
    int o    = bid & 127;
    const float* w = conv ? w2 : w1;
    const float* s = conv ? s2 : s1;
    int i = threadIdx.x;
    float sv = s[b * C + i] + 1.0f;
    const float* wp = w + (o * C + i) * 9;
    float sum = 0.f;
    #pragma unroll
    for (int k = 0; k < 9; ++k) { float t = wp[k] * sv; sum += t * t; }
    #pragma unroll
    for (int off = 32; off; off >>= 1) sum += __shfl_down(sum, off);
    __shared__ float red[2];
    if ((threadIdx.x & 63) == 0) red[threadIdx.x >> 6] = sum;
    __syncthreads();
    if (threadIdx.x == 0) d[bid] = rsqrtf(red[0] + red[1] + EPSV);
}

// ---------------------------------------------------------------------------
// expand -> wave-coalesced B-fragment tiling:
// wm[cb][tap][ocT=oc>>4][icC=ic>>5][(oc&15)*32 + (ic&31)]   (bf16)
// ---------------------------------------------------------------------------
__global__ __launch_bounds__(256) void expand_kernel(
    const float* __restrict__ w1, const float* __restrict__ w2,
    const float* __restrict__ s1, const float* __restrict__ s2,
    const float* __restrict__ d, short* __restrict__ wm)
{
    int idx = blockIdx.x * 256 + threadIdx.x;
    int ic  = idx & 127;
    int oc  = (idx >> 7) & 127;
    int t   = idx >> 14;            // cb*9+tap, < 288
    int tap = t % 9;
    int cb  = t / 9;                // conv*16+b
    int b   = cb & 15;
    int conv= cb >> 4;
    const float* w = conv ? w2 : w1;
    const float* s = conv ? s2 : s1;
    float v = w[(oc * C + ic) * 9 + tap] * (s[b * C + ic] + 1.0f)
            * d[(conv * B + b) * C + oc];
    int dst = cb * 147456
            + ((tap * 8 + (oc >> 4)) * 4 + (ic >> 5)) * 512
            + (oc & 15) * 32 + (ic & 31);
    wm[dst] = f2bs(v);
}

// ---------------------------------------------------------------------------
// dwexpand: dwm[tap][ocT=oc>>4 (16)][icC=ic>>5 (4)][(oc&15)*32+(ic&31)]
// ---------------------------------------------------------------------------
__global__ __launch_bounds__(256) void dwexpand_kernel(
    const float* __restrict__ dw, short* __restrict__ dwm)
{
    int idx = blockIdx.x * 256 + threadIdx.x;   // 16*256*128 = 524288
    int ic  = idx & 127;
    int oc  = (idx >> 7) & 255;
    int tap = idx >> 15;
    int dst = ((tap * 16 + (oc >> 4)) * 4 + (ic >> 5)) * 512
            + (oc & 15) * 32 + (ic & 31);
    dwm[dst] = f2bs(dw[(oc * C + ic) * 16 + tap]);
}

// ---------------------------------------------------------------------------
// nchw(f32) -> nhwc(bf16) transpose of features.
// ---------------------------------------------------------------------------
__global__ __launch_bounds__(256) void nchw2nhwc_kernel(
    const float* __restrict__ in, short* __restrict__ out)
{
    __shared__ short s[128 * 136];
    int bid = blockIdx.x;                   // b*128 + h
    int h = bid & 127, b = bid >> 7;
    int tid = threadIdx.x;
    for (int i = tid; i < 128 * 32; i += 256) {
        int w4 = i & 31, ic = i >> 5;
        float4 v = *(const float4*)&in[((b * C + ic) * H + h) * W + w4 * 4];
        s[(w4 * 4 + 0) * 136 + ic] = f2bs(v.x);
        s[(w4 * 4 + 1) * 136 + ic] = f2bs(v.y);
        s[(w4 * 4 + 2) * 136 + ic] = f2bs(v.z);
        s[(w4 * 4 + 3) * 136 + ic] = f2bs(v.w);
    }
    __syncthreads();
    for (int i = tid; i < 128 * 16; i += 256) {
        int icg = i & 15, w = i >> 4;
        *(uint4*)&out[((b * H + h) * W + w) * C + icg * 8] =
            *(uint4*)&s[w * 136 + icg * 8];
    }
}

// ---------------------------------------------------------------------------
// conv3x3 MFMA implicit GEMM, register-double-buffered K pipeline.
// block tile: 128 px (8h x 16w) x 128 oc; wave: 64 px x 64 oc.
// K steps: 9 taps x 4 ic-chunks = 36; prefetch step s+1 during MFMAs of s.
// + T5 setprio around the MFMA cluster (3 blocks/CU -> phase diversity).
// ---------------------------------------------------------------------------
__global__ __launch_bounds__(256, 3) void conv3x3_mfma(
    const short* __restrict__ in, const short* __restrict__ wmc,
    const short* __restrict__ res, short* __restrict__ out)
{
    __shared__ short sIn[10 * 18 * 136];   // 48,960 B

    int bid = blockIdx.x;
    int wt = bid & 7, ht = (bid >> 3) & 15, b = bid >> 7;
    int w0 = wt * 16, h0 = ht * 8;
    int tid  = threadIdx.x;
    int lane = tid & 63, wv = tid >> 6;
    int q = lane >> 4, l15 = lane & 15;
    int wr = wv & 1;       // row half
    int wc = wv >> 1;      // oc half

    for (int i = tid; i < 10 * 18 * 16; i += 256) {
        int icg = i & 15;
        int t = i >> 4;
        int wl = t % 18, hl = t / 18;
        int gh = h0 - 1 + hl, gw = w0 - 1 + wl;
        uint4 v = make_uint4(0u, 0u, 0u, 0u);
        if ((unsigned)gh < (unsigned)H && (unsigned)gw < (unsigned)W)
            v = *(const uint4*)&in[((b * H + gh) * W + gw) * C + icg * 8];
        *(uint4*)&sIn[(hl * 18 + wl) * 136 + icg * 8] = v;
    }
    __syncthreads();

    const short* wb = wmc + b * 147456;

    f32x4 acc[4][4];
    #pragma unroll
    for (int mt = 0; mt < 4; ++mt)
        #pragma unroll
        for (int nt = 0; nt < 4; ++nt)
            acc[mt][nt] = (f32x4){0.f, 0.f, 0.f, 0.f};

    bf16x8 af[2][4], bf[2][4];

    // prologue: (tap=0 -> dh=0,dw=0, c=0) into parity 0
    #pragma unroll
    for (int mt = 0; mt < 4; ++mt)
        af[0][mt] = *(const bf16x8*)&sIn[((wr * 4 + mt) * 18 + l15) * 136 + q * 8];
    #pragma unroll
    for (int nt = 0; nt < 4; ++nt)
        bf[0][nt] = *(const bf16x8*)&wb[((0 * 8 + wc * 4 + nt) * 4 + 0) * 512
                                        + l15 * 32 + q * 8];

    #pragma unroll 1
    for (int tap = 0; tap < 9; ++tap) {
        int dh  = tap / 3,  dwd = tap - dh * 3;
        int tapn = (tap + 1 < 9) ? tap + 1 : tap;   // dummy prefetch on last
        int dhn = tapn / 3, dwn = tapn - dhn * 3;
        #pragma unroll
        for (int c = 0; c < 4; ++c) {
            int p  = c & 1, pn = p ^ 1;
            int cn = (c + 1) & 3;
            int tE  = (c == 3) ? tapn : tap;
            int dhE = (c == 3) ? dhn : dh;
            int dwE = (c == 3) ? dwn : dwd;
            // prefetch step s+1
            #pragma unroll
            for (int mt = 0; mt < 4; ++mt)
                af[pn][mt] = *(const bf16x8*)&sIn[((wr * 4 + mt + dhE) * 18 + l15 + dwE) * 136
                                                  + cn * 32 + q * 8];
            #pragma unroll
            for (int nt = 0; nt < 4; ++nt)
                bf[pn][nt] = *(const bf16x8*)&wb[((tE * 8 + wc * 4 + nt) * 4 + cn) * 512
                                                 + l15 * 32 + q * 8];
            // compute step s (T5: favor MFMA waves while others stage/load)
            __builtin_amdgcn_s_setprio(1);
            #pragma unroll
            for (int mt = 0; mt < 4; ++mt)
                #pragma unroll
                for (int nt = 0; nt < 4; ++nt)
                    acc[mt][nt] = __builtin_amdgcn_mfma_f32_16x16x32_bf16(
                        af[p][mt], bf[p][nt], acc[mt][nt], 0, 0, 0);
            __builtin_amdgcn_s_setprio(0);
        }
    }

    bool has_res = (res != nullptr);
    #pragma unroll
    for (int mt = 0; mt < 4; ++mt) {
        int h = h0 + wr * 4 + mt;
        #pragma unroll
        for (int nt = 0; nt < 4; ++nt) {
            int oc = wc * 64 + nt * 16 + l15;
            #pragma unroll
            for (int reg = 0; reg < 4; ++reg) {
                int w = w0 + q * 4 + reg;
                int idx = ((b * H + h) * W + w) * C + oc;
                float v = acc[mt][nt][reg];
                if (has_res) v += bs2f(res[idx]);
                v = v >= 0.f ? v : SLOPE * v;
                out[idx] = f2bs(v);
            }
        }
    }
}

// ---------------------------------------------------------------------------
// downconv MFMA — round-2 structure (proven 191 us, clean counters).
//  - A (weights, global/L2): 4-slot register ring, prefetch 3 K-steps ahead.
//  - Input staging: direct barrier-bracketed stage per ic-chunk.
//  - + T5 setprio around the MFMA cluster (2 blocks/CU phase diversity).
//  LESSONS (do not regress):
//   r1: +pre[11] T14 staging -> >128 arch VGPR -> scratch spill (WRITE 488MB).
//   r3: 4oh-tile/double-buffer/1-barrier restructure -> FETCH 373MB, 333us.
//       Grid=1024 = 4 blocks/CU of work: residency 2 vs 3 both take 2 rounds,
//       so LDS-shrink-for-occupancy has no payoff at this grid quantization.
// ---------------------------------------------------------------------------
__global__ __launch_bounds__(256, 2) void downconv_mfma(
    const short* __restrict__ in, const short* __restrict__ dwm,
    const float* __restrict__ db, float* __restrict__ out)
{
    __shared__ short sIn[19 * 2 * 18 * 40];   // 54,720 B

    int bid = blockIdx.x;
    int wt = bid & 3;  bid >>= 2;
    int ht = bid & 7;  bid >>= 3;
    int ot = bid & 1;  bid >>= 1;
    int b  = bid;
    int ow0 = wt * 16, oh0 = ht * 8, oc0 = ot * 128;

    int tid  = threadIdx.x;
    int lane = tid & 63, wv = tid >> 6;
    int q = lane >> 4, l15 = lane & 15;
    int wo = wv & 1;
    int wp = wv >> 1;

    f32x4 acc[4][4];
    #pragma unroll
    for (int mt = 0; mt < 4; ++mt)
        #pragma unroll
        for (int nt = 0; nt < 4; ++nt)
            acc[mt][nt] = (f32x4){0.f, 0.f, 0.f, 0.f};

    int ocTb = ot * 8 + wo * 4;   // this wave's oc-tile base (16-oc units)

    // ---- direct stage of ic-chunk 0 ----
    for (int i = tid; i < 19 * 35 * 4; i += 256) {
        int icg = i & 3;
        int t = i >> 2;
        int wl = t % 35, hl = t / 35;
        int gh = 2 * oh0 - 1 + hl, gw = 2 * ow0 - 1 + wl;
        uint4 v = make_uint4(0u, 0u, 0u, 0u);
        if ((unsigned)gh < (unsigned)H && (unsigned)gw < (unsigned)W)
            v = *(const uint4*)&in[((b * H + gh) * W + gw) * C + icg * 8];
        *(uint4*)&sIn[((hl * 2 + (wl & 1)) * 18 + (wl >> 1)) * 40 + icg * 8] = v;
    }

    bf16x8 af[4][4];   // A ring: slot = (c*16+tap) & 3, filled 3 steps ahead
    bf16x8 bf[2][4];   // B parity: slot = tap & 1

    // A-pipeline prologue: steps 0..2 (c=0, taps 0..2) — no LDS dependence
    #pragma unroll
    for (int s = 0; s < 3; ++s)
        #pragma unroll
        for (int mt = 0; mt < 4; ++mt)
            af[s][mt] = *(const bf16x8*)&dwm[((s * 16 + ocTb + mt) * 4 + 0) * 512
                                             + l15 * 32 + q * 8];

    __syncthreads();

    #pragma unroll 1
    for (int c = 0; c < 4; ++c) {
        // B prologue: tap 0 (dh=0, dw=0)
        #pragma unroll
        for (int nt = 0; nt < 4; ++nt) {
            int hl = 2 * (wp * 4 + nt);
            bf[0][nt] = *(const bf16x8*)&sIn[(hl * 2 * 18 + l15) * 40 + q * 8];
        }

        #pragma unroll
        for (int tap = 0; tap < 16; ++tap) {
            // A prefetch: flattened step s+3 (crosses the c boundary)
            {
                int sp = c * 16 + tap + 3;
                sp = sp < 63 ? sp : 63;          // dummy tail prefetch
                int pc = sp >> 4, pt = sp & 15;
                #pragma unroll
                for (int mt = 0; mt < 4; ++mt)
                    af[(tap + 3) & 3][mt] =
                        *(const bf16x8*)&dwm[((pt * 16 + ocTb + mt) * 4 + pc) * 512
                                             + l15 * 32 + q * 8];
            }
            // B prefetch: tap+1
            {
                int tapn = (tap + 1 < 16) ? tap + 1 : tap;
                int dhn = tapn >> 2, dwn = tapn & 3;
                #pragma unroll
                for (int nt = 0; nt < 4; ++nt) {
                    int hl = 2 * (wp * 4 + nt) + dhn;
                    bf[(tap + 1) & 1][nt] =
                        *(const bf16x8*)&sIn[((hl * 2 + (dwn & 1)) * 18 + l15 + (dwn >> 1)) * 40
                                             + q * 8];
                }
            }
            // compute tap (T5)
            __builtin_amdgcn_s_setprio(1);
            #pragma unroll
            for (int mt = 0; mt < 4; ++mt)
                #pragma unroll
                for (int nt = 0; nt < 4; ++nt)
                    acc[mt][nt] = __builtin_amdgcn_mfma_f32_16x16x32_bf16(
                        af[tap & 3][mt], bf[tap & 1][nt], acc[mt][nt], 0, 0, 0);
            __builtin_amdgcn_s_setprio(0);
        }

        if (c < 3) {
            __syncthreads();                     // all reads of chunk c done
            for (int i = tid; i < 19 * 35 * 4; i += 256) {
                int icg = i & 3;
                int t = i >> 2;
                int wl = t % 35, hl = t / 35;
                int gh = 2 * oh0 - 1 + hl, gw = 2 * ow0 - 1 + wl;
                uint4 v = make_uint4(0u, 0u, 0u, 0u);
                if ((unsigned)gh < (unsigned)H && (unsigned)gw < (unsigned)W)
                    v = *(const uint4*)&in[((b * H + gh) * W + gw) * C
                                           + (c + 1) * 32 + icg * 8];
                *(uint4*)&sIn[((hl * 2 + (wl & 1)) * 18 + (wl >> 1)) * 40 + icg * 8] = v;
            }
            __syncthreads();                     // chunk c+1 visible
        }
    }

    #pragma unroll
    for (int mt = 0; mt < 4; ++mt) {
        #pragma unroll
        for (int reg = 0; reg < 4; ++reg) {
            int oc = oc0 + wo * 64 + mt * 16 + q * 4 + reg;
            float bias = db[oc];
            #pragma unroll
            for (int nt = 0; nt < 4; ++nt) {
                int oh = oh0 + wp * 4 + nt;
                int ow = ow0 + l15;
                out[((b * CO + oc) * HO + oh) * WO + ow] = acc[mt][nt][reg] + bias;
            }
        }
    }
}

// ---------------------------------------------------------------------------
extern "C" void kernel_launch(void* const* d_in, const int* in_sizes, int n_in,
                              void* d_out, int out_size, void* d_ws, size_t ws_size,
                              hipStream_t stream) {
    const float* features = (const float*)d_in[0];
    const float* sm1      = (const float*)d_in[1];   // style_mean1 -> s1
    const float* ss1      = (const float*)d_in[2];   // style_std1  -> s2 (per reference)
    const float* w1       = (const float*)d_in[6];
    const float* w2       = (const float*)d_in[7];
    const float* dw       = (const float*)d_in[8];
    const float* db       = (const float*)d_in[9];
    float* out = (float*)d_out;

    char* ws = (char*)d_ws;
    short* x1  = (short*)ws;                              // 67,108,864 B
    short* x2  = (short*)(ws + 67108864);                 // 67,108,864 B (also fx)
    short* wm  = (short*)(ws + 134217728);                // 9,437,184 B
    short* dwm = (short*)(ws + 143654912);                // 1,048,576 B
    float* dv  = (float*)(ws + 144703488);                // 16,384 B

    demod_kernel    <<<4096, 128, 0, stream>>>(w1, w2, sm1, ss1, dv);
    expand_kernel   <<<18432, 256, 0, stream>>>(w1, w2, sm1, ss1, dv, wm);
    dwexpand_kernel <<<2048, 256, 0, stream>>>(dw, dwm);
    nchw2nhwc_kernel<<<2048, 256, 0, stream>>>(features, x2);
    conv3x3_mfma    <<<2048, 256, 0, stream>>>(x2, wm, nullptr, x1);
    conv3x3_mfma    <<<2048, 256, 0, stream>>>(x1, wm + 16 * 147456, x1, x2);
    downconv_mfma   <<<1024, 256, 0, stream>>>(x2, dwm, db, out);
}

// Round 5
// 541.902 us; speedup vs baseline: 1.4888x; 1.0041x over previous
//
#include <hip/hip_runtime.h>
#include <hip/hip_bf16.h>

constexpr int B  = 16;
constexpr int C  = 128;
constexpr int H  = 128;
constexpr int W  = 128;
constexpr int CO = 256;
constexpr int HO = 64;
constexpr int WO = 64;

#define EPSV   1e-8f
#define SLOPE  0.2f

typedef short bf16x8 __attribute__((ext_vector_type(8)));
typedef float f32x4  __attribute__((ext_vector_type(4)));

__device__ __forceinline__ short f2bs(float v) {
    __hip_bfloat16 h = __float2bfloat16(v);
    return *(short*)&h;
}
__device__ __forceinline__ float bs2f(short s) {
    __hip_bfloat16 h = *(__hip_bfloat16*)&s;
    return __bfloat162float(h);
}

// ---------------------------------------------------------------------------
// demod: d[conv][b][o] = rsqrt(sum_{i,k}(w[o,i,k]*(s[b,i]+1))^2 + eps)
// ---------------------------------------------------------------------------
__global__ __launch_bounds__(128) void demod_kernel(
    const float* __restrict__ w1, const float* __restrict__ w2,
    const float* __restrict__ s1, const float* __restrict__ s2,
    float* __restrict__ d)
{
    int bid  = blockIdx.x;          // conv*2048 + b*128 + o
    int conv = bid >> 11;
    int b    = (bid >> 7) & 15;
    int o    = bid & 127;
    const float* w = conv ? w2 : w1;
    const float* s = conv ? s2 : s1;
    int i = threadIdx.x;
    float sv = s[b * C + i] + 1.0f;
    const float* wp = w + (o * C + i) * 9;
    float sum = 0.f;
    #pragma unroll
    for (int k = 0; k < 9; ++k) { float t = wp[k] * sv; sum += t * t; }
    #pragma unroll
    for (int off = 32; off; off >>= 1) sum += __shfl_down(sum, off);
    __shared__ float red[2];
    if ((threadIdx.x & 63) == 0) red[threadIdx.x >> 6] = sum;
    __syncthreads();
    if (threadIdx.x == 0) d[bid] = rsqrtf(red[0] + red[1] + EPSV);
}

// ---------------------------------------------------------------------------
// expand -> wave-coalesced B-fragment tiling:
// wm[cb][tap][ocT=oc>>4][icC=ic>>5][(oc&15)*32 + (ic&31)]   (bf16)
// ---------------------------------------------------------------------------
__global__ __launch_bounds__(256) void expand_kernel(
    const float* __restrict__ w1, const float* __restrict__ w2,
    const float* __restrict__ s1, const float* __restrict__ s2,
    const float* __restrict__ d, short* __restrict__ wm)
{
    int idx = blockIdx.x * 256 + threadIdx.x;
    int ic  = idx & 127;
    int oc  = (idx >> 7) & 127;
    int t   = idx >> 14;            // cb*9+tap, < 288
    int tap = t % 9;
    int cb  = t / 9;                // conv*16+b
    int b   = cb & 15;
    int conv= cb >> 4;
    const float* w = conv ? w2 : w1;
    const float* s = conv ? s2 : s1;
    float v = w[(oc * C + ic) * 9 + tap] * (s[b * C + ic] + 1.0f)
            * d[(conv * B + b) * C + oc];
    int dst = cb * 147456
            + ((tap * 8 + (oc >> 4)) * 4 + (ic >> 5)) * 512
            + (oc & 15) * 32 + (ic & 31);
    wm[dst] = f2bs(v);
}

// ---------------------------------------------------------------------------
// dwexpand: dwm[tap][ocT=oc>>4 (16)][icC=ic>>5 (4)][(oc&15)*32+(ic&31)]
// ---------------------------------------------------------------------------
__global__ __launch_bounds__(256) void dwexpand_kernel(
    const float* __restrict__ dw, short* __restrict__ dwm)
{
    int idx = blockIdx.x * 256 + threadIdx.x;   // 16*256*128 = 524288
    int ic  = idx & 127;
    int oc  = (idx >> 7) & 255;
    int tap = idx >> 15;
    int dst = ((tap * 16 + (oc >> 4)) * 4 + (ic >> 5)) * 512
            + (oc & 15) * 32 + (ic & 31);
    dwm[dst] = f2bs(dw[(oc * C + ic) * 16 + tap]);
}

// ---------------------------------------------------------------------------
// nchw(f32) -> nhwc(bf16) transpose of features.
// ---------------------------------------------------------------------------
__global__ __launch_bounds__(256) void nchw2nhwc_kernel(
    const float* __restrict__ in, short* __restrict__ out)
{
    __shared__ short s[128 * 136];
    int bid = blockIdx.x;                   // b*128 + h
    int h = bid & 127, b = bid >> 7;
    int tid = threadIdx.x;
    for (int i = tid; i < 128 * 32; i += 256) {
        int w4 = i & 31, ic = i >> 5;
        float4 v = *(const float4*)&in[((b * C + ic) * H + h) * W + w4 * 4];
        s[(w4 * 4 + 0) * 136 + ic] = f2bs(v.x);
        s[(w4 * 4 + 1) * 136 + ic] = f2bs(v.y);
        s[(w4 * 4 + 2) * 136 + ic] = f2bs(v.z);
        s[(w4 * 4 + 3) * 136 + ic] = f2bs(v.w);
    }
    __syncthreads();
    for (int i = tid; i < 128 * 16; i += 256) {
        int icg = i & 15, w = i >> 4;
        *(uint4*)&out[((b * H + h) * W + w) * C + icg * 8] =
            *(uint4*)&s[w * 136 + icg * 8];
    }
}

// ---------------------------------------------------------------------------
// conv3x3 MFMA implicit GEMM.
// Round-5: flattened 36-step fully-unrolled K loop; B (global weight)
// fragments in a 3-slot ring at prefetch distance 2 (covers ~2x78cy of MFMA
// against ~200cy L2 latency; distance-1 exposed ~150cy/step -> MfmaUtil 22%).
// A (LDS pixel) fragments stay distance-1 (LDS latency ~120cy, mostly covered).
// Register math (r1 lesson): 80 arch + 16 (bf ring+1) + 64 acc ~= 160 unified
// <= 168 cap for 3 waves/SIMD at launch_bounds(256,3). bf[4] would be 176 ->
// spill; rejected. All ring indices compile-time (rule #20: no dynamic
// ext_vector indexing).
// ---------------------------------------------------------------------------
__global__ __launch_bounds__(256, 3) void conv3x3_mfma(
    const short* __restrict__ in, const short* __restrict__ wmc,
    const short* __restrict__ res, short* __restrict__ out)
{
    __shared__ short sIn[10 * 18 * 136];   // 48,960 B

    int bid = blockIdx.x;
    int wt = bid & 7, ht = (bid >> 3) & 15, b = bid >> 7;
    int w0 = wt * 16, h0 = ht * 8;
    int tid  = threadIdx.x;
    int lane = tid & 63, wv = tid >> 6;
    int q = lane >> 4, l15 = lane & 15;
    int wr = wv & 1;       // row half
    int wc = wv >> 1;      // oc half

    for (int i = tid; i < 10 * 18 * 16; i += 256) {
        int icg = i & 15;
        int t = i >> 4;
        int wl = t % 18, hl = t / 18;
        int gh = h0 - 1 + hl, gw = w0 - 1 + wl;
        uint4 v = make_uint4(0u, 0u, 0u, 0u);
        if ((unsigned)gh < (unsigned)H && (unsigned)gw < (unsigned)W)
            v = *(const uint4*)&in[((b * H + gh) * W + gw) * C + icg * 8];
        *(uint4*)&sIn[(hl * 18 + wl) * 136 + icg * 8] = v;
    }
    __syncthreads();

    const short* wb = wmc + b * 147456;

    f32x4 acc[4][4];
    #pragma unroll
    for (int mt = 0; mt < 4; ++mt)
        #pragma unroll
        for (int nt = 0; nt < 4; ++nt)
            acc[mt][nt] = (f32x4){0.f, 0.f, 0.f, 0.f};

    bf16x8 af[2][4];   // pixels (LDS), parity s&1, distance 1
    bf16x8 bf[3][4];   // weights (global), ring s%3, distance 2

    // K-step s = tap*4 + c  (tap = s>>2 since 36 = 9*4, c = s&3)
    auto ldAF = [&](int slot, int tap, int c) {
        int dh = tap / 3, dw = tap - dh * 3;
        #pragma unroll
        for (int mt = 0; mt < 4; ++mt)
            af[slot][mt] = *(const bf16x8*)&sIn[((wr * 4 + mt + dh) * 18 + l15 + dw) * 136
                                                + c * 32 + q * 8];
    };
    auto ldBF = [&](int slot, int tap, int c) {
        #pragma unroll
        for (int nt = 0; nt < 4; ++nt)
            bf[slot][nt] = *(const bf16x8*)&wb[((tap * 8 + wc * 4 + nt) * 4 + c) * 512
                                               + l15 * 32 + q * 8];
    };

    // prologue: af step 0; bf steps 0,1
    ldAF(0, 0, 0);
    ldBF(0, 0, 0);
    ldBF(1, 0, 1);

    #pragma unroll
    for (int s = 0; s < 36; ++s) {
        // issue global (long-latency) prefetch first: step s+2 into ring slot
        int s2 = (s + 2 < 36) ? s + 2 : s;       // dummy at tail
        ldBF((s + 2) % 3, s2 >> 2, s2 & 3);
        // LDS prefetch: step s+1
        int s1 = (s + 1 < 36) ? s + 1 : s;       // dummy at tail
        ldAF((s + 1) & 1, s1 >> 2, s1 & 3);
        // compute step s (T5: favor MFMA waves while others stage/load)
        __builtin_amdgcn_s_setprio(1);
        #pragma unroll
        for (int mt = 0; mt < 4; ++mt)
            #pragma unroll
            for (int nt = 0; nt < 4; ++nt)
                acc[mt][nt] = __builtin_amdgcn_mfma_f32_16x16x32_bf16(
                    af[s & 1][mt], bf[s % 3][nt], acc[mt][nt], 0, 0, 0);
        __builtin_amdgcn_s_setprio(0);
    }

    bool has_res = (res != nullptr);
    #pragma unroll
    for (int mt = 0; mt < 4; ++mt) {
        int h = h0 + wr * 4 + mt;
        #pragma unroll
        for (int nt = 0; nt < 4; ++nt) {
            int oc = wc * 64 + nt * 16 + l15;
            #pragma unroll
            for (int reg = 0; reg < 4; ++reg) {
                int w = w0 + q * 4 + reg;
                int idx = ((b * H + h) * W + w) * C + oc;
                float v = acc[mt][nt][reg];
                if (has_res) v += bs2f(res[idx]);
                v = v >= 0.f ? v : SLOPE * v;
                out[idx] = f2bs(v);
            }
        }
    }
}

// ---------------------------------------------------------------------------
// downconv MFMA — round-2 structure + T5 setprio (warm ~<144 us in r4).
//  - A (weights, global/L2): 4-slot register ring, prefetch 3 K-steps ahead.
//  - Input staging: direct barrier-bracketed stage per ic-chunk.
//  LESSONS (do not regress):
//   r1: +pre[11] T14 staging -> >128 arch VGPR -> scratch spill (WRITE 488MB).
//   r3: 4oh-tile/double-buffer/1-barrier restructure -> FETCH 373MB, 333us.
//       Grid=1024 = 4 blocks/CU of work: residency 2 vs 3 both take 2 rounds,
//       so LDS-shrink-for-occupancy has no payoff at this grid quantization.
//   r4: T5 setprio around MFMA cluster: 191 -> <144 us. Keep.
// ---------------------------------------------------------------------------
__global__ __launch_bounds__(256, 2) void downconv_mfma(
    const short* __restrict__ in, const short* __restrict__ dwm,
    const float* __restrict__ db, float* __restrict__ out)
{
    __shared__ short sIn[19 * 2 * 18 * 40];   // 54,720 B

    int bid = blockIdx.x;
    int wt = bid & 3;  bid >>= 2;
    int ht = bid & 7;  bid >>= 3;
    int ot = bid & 1;  bid >>= 1;
    int b  = bid;
    int ow0 = wt * 16, oh0 = ht * 8, oc0 = ot * 128;

    int tid  = threadIdx.x;
    int lane = tid & 63, wv = tid >> 6;
    int q = lane >> 4, l15 = lane & 15;
    int wo = wv & 1;
    int wp = wv >> 1;

    f32x4 acc[4][4];
    #pragma unroll
    for (int mt = 0; mt < 4; ++mt)
        #pragma unroll
        for (int nt = 0; nt < 4; ++nt)
            acc[mt][nt] = (f32x4){0.f, 0.f, 0.f, 0.f};

    int ocTb = ot * 8 + wo * 4;   // this wave's oc-tile base (16-oc units)

    // ---- direct stage of ic-chunk 0 ----
    for (int i = tid; i < 19 * 35 * 4; i += 256) {
        int icg = i & 3;
        int t = i >> 2;
        int wl = t % 35, hl = t / 35;
        int gh = 2 * oh0 - 1 + hl, gw = 2 * ow0 - 1 + wl;
        uint4 v = make_uint4(0u, 0u, 0u, 0u);
        if ((unsigned)gh < (unsigned)H && (unsigned)gw < (unsigned)W)
            v = *(const uint4*)&in[((b * H + gh) * W + gw) * C + icg * 8];
        *(uint4*)&sIn[((hl * 2 + (wl & 1)) * 18 + (wl >> 1)) * 40 + icg * 8] = v;
    }

    bf16x8 af[4][4];   // A ring: slot = (c*16+tap) & 3, filled 3 steps ahead
    bf16x8 bf[2][4];   // B parity: slot = tap & 1

    // A-pipeline prologue: steps 0..2 (c=0, taps 0..2) — no LDS dependence
    #pragma unroll
    for (int s = 0; s < 3; ++s)
        #pragma unroll
        for (int mt = 0; mt < 4; ++mt)
            af[s][mt] = *(const bf16x8*)&dwm[((s * 16 + ocTb + mt) * 4 + 0) * 512
                                             + l15 * 32 + q * 8];

    __syncthreads();

    #pragma unroll 1
    for (int c = 0; c < 4; ++c) {
        // B prologue: tap 0 (dh=0, dw=0)
        #pragma unroll
        for (int nt = 0; nt < 4; ++nt) {
            int hl = 2 * (wp * 4 + nt);
            bf[0][nt] = *(const bf16x8*)&sIn[(hl * 2 * 18 + l15) * 40 + q * 8];
        }

        #pragma unroll
        for (int tap = 0; tap < 16; ++tap) {
            // A prefetch: flattened step s+3 (crosses the c boundary)
            {
                int sp = c * 16 + tap + 3;
                sp = sp < 63 ? sp : 63;          // dummy tail prefetch
                int pc = sp >> 4, pt = sp & 15;
                #pragma unroll
                for (int mt = 0; mt < 4; ++mt)
                    af[(tap + 3) & 3][mt] =
                        *(const bf16x8*)&dwm[((pt * 16 + ocTb + mt) * 4 + pc) * 512
                                             + l15 * 32 + q * 8];
            }
            // B prefetch: tap+1
            {
                int tapn = (tap + 1 < 16) ? tap + 1 : tap;
                int dhn = tapn >> 2, dwn = tapn & 3;
                #pragma unroll
                for (int nt = 0; nt < 4; ++nt) {
                    int hl = 2 * (wp * 4 + nt) + dhn;
                    bf[(tap + 1) & 1][nt] =
                        *(const bf16x8*)&sIn[((hl * 2 + (dwn & 1)) * 18 + l15 + (dwn >> 1)) * 40
                                             + q * 8];
                }
            }
            // compute tap (T5)
            __builtin_amdgcn_s_setprio(1);
            #pragma unroll
            for (int mt = 0; mt < 4; ++mt)
                #pragma unroll
                for (int nt = 0; nt < 4; ++nt)
                    acc[mt][nt] = __builtin_amdgcn_mfma_f32_16x16x32_bf16(
                        af[tap & 3][mt], bf[tap & 1][nt], acc[mt][nt], 0, 0, 0);
            __builtin_amdgcn_s_setprio(0);
        }

        if (c < 3) {
            __syncthreads();                     // all reads of chunk c done
            for (int i = tid; i < 19 * 35 * 4; i += 256) {
                int icg = i & 3;
                int t = i >> 2;
                int wl = t % 35, hl = t / 35;
                int gh = 2 * oh0 - 1 + hl, gw = 2 * ow0 - 1 + wl;
                uint4 v = make_uint4(0u, 0u, 0u, 0u);
                if ((unsigned)gh < (unsigned)H && (unsigned)gw < (unsigned)W)
                    v = *(const uint4*)&in[((b * H + gh) * W + gw) * C
                                           + (c + 1) * 32 + icg * 8];
                *(uint4*)&sIn[((hl * 2 + (wl & 1)) * 18 + (wl >> 1)) * 40 + icg * 8] = v;
            }
            __syncthreads();                     // chunk c+1 visible
        }
    }

    #pragma unroll
    for (int mt = 0; mt < 4; ++mt) {
        #pragma unroll
        for (int reg = 0; reg < 4; ++reg) {
            int oc = oc0 + wo * 64 + mt * 16 + q * 4 + reg;
            float bias = db[oc];
            #pragma unroll
            for (int nt = 0; nt < 4; ++nt) {
                int oh = oh0 + wp * 4 + nt;
                int ow = ow0 + l15;
                out[((b * CO + oc) * HO + oh) * WO + ow] = acc[mt][nt][reg] + bias;
            }
        }
    }
}

// ---------------------------------------------------------------------------
extern "C" void kernel_launch(void* const* d_in, const int* in_sizes, int n_in,
                              void* d_out, int out_size, void* d_ws, size_t ws_size,
                              hipStream_t stream) {
    const float* features = (const float*)d_in[0];
    const float* sm1      = (const float*)d_in[1];   // style_mean1 -> s1
    const float* ss1      = (const float*)d_in[2];   // style_std1  -> s2 (per reference)
    const float* w1       = (const float*)d_in[6];
    const float* w2       = (const float*)d_in[7];
    const float* dw       = (const float*)d_in[8];
    const float* db       = (const float*)d_in[9];
    float* out = (float*)d_out;

    char* ws = (char*)d_ws;
    short* x1  = (short*)ws;                              // 67,108,864 B
    short* x2  = (short*)(ws + 67108864);                 // 67,108,864 B (also fx)
    short* wm  = (short*)(ws + 134217728);                // 9,437,184 B
    short* dwm = (short*)(ws + 143654912);                // 1,048,576 B
    float* dv  = (float*)(ws + 144703488);                // 16,384 B

    demod_kernel    <<<4096, 128, 0, stream>>>(w1, w2, sm1, ss1, dv);
    expand_kernel   <<<18432, 256, 0, stream>>>(w1, w2, sm1, ss1, dv, wm);
    dwexpand_kernel <<<2048, 256, 0, stream>>>(dw, dwm);
    nchw2nhwc_kernel<<<2048, 256, 0, stream>>>(features, x2);
    conv3x3_mfma    <<<2048, 256, 0, stream>>>(x2, wm, nullptr, x1);
    conv3x3_mfma    <<<2048, 256, 0, stream>>>(x1, wm + 16 * 147456, x1, x2);
    downconv_mfma   <<<1024, 256, 0, stream>>>(x2, dwm, db, out);
}

// Round 6
// 536.413 us; speedup vs baseline: 1.5040x; 1.0102x over previous
//
#include <hip/hip_runtime.h>
#include <hip/hip_bf16.h>

constexpr int B  = 16;
constexpr int C  = 128;
constexpr int H  = 128;
constexpr int W  = 128;
constexpr int CO = 256;
constexpr int HO = 64;
constexpr int WO = 64;

#define EPSV   1e-8f
#define SLOPE  0.2f

typedef short bf16x8 __attribute__((ext_vector_type(8)));
typedef float f32x4  __attribute__((ext_vector_type(4)));

__device__ __forceinline__ short f2bs(float v) {
    __hip_bfloat16 h = __float2bfloat16(v);
    return *(short*)&h;
}
__device__ __forceinline__ float bs2f(short s) {
    __hip_bfloat16 h = *(__hip_bfloat16*)&s;
    return __bfloat162float(h);
}

// ---------------------------------------------------------------------------
// demod: d[conv][b][o] = rsqrt(sum_{i,k}(w[o,i,k]*(s[b,i]+1))^2 + eps)
// ---------------------------------------------------------------------------
__global__ __launch_bounds__(128) void demod_kernel(
    const float* __restrict__ w1, const float* __restrict__ w2,
    const float* __restrict__ s1, const float* __restrict__ s2,
    float* __restrict__ d)
{
    int bid  = blockIdx.x;          // conv*2048 + b*128 + o
    int conv = bid >> 11;
    int b    = (bid >> 7) & 15;
    int o    = bid & 127;
    const float* w = conv ? w2 : w1;
    const float* s = conv ? s2 : s1;
    int i = threadIdx.x;
    float sv = s[b * C + i] + 1.0f;
    const float* wp = w + (o * C + i) * 9;
    float sum = 0.f;
    #pragma unroll
    for (int k = 0; k < 9; ++k) { float t = wp[k] * sv; sum += t * t; }
    #pragma unroll
    for (int off = 32; off; off >>= 1) sum += __shfl_down(sum, off);
    __shared__ float red[2];
    if ((threadIdx.x & 63) == 0) red[threadIdx.x >> 6] = sum;
    __syncthreads();
    if (threadIdx.x == 0) d[bid] = rsqrtf(red[0] + red[1] + EPSV);
}

// ---------------------------------------------------------------------------
// expand -> wave-coalesced B-fragment tiling:
// wm[cb][tap][ocT=oc>>4][icC=ic>>5][(oc&15)*32 + (ic&31)]   (bf16)
// ---------------------------------------------------------------------------
__global__ __launch_bounds__(256) void expand_kernel(
    const float* __restrict__ w1, const float* __restrict__ w2,
    const float* __restrict__ s1, const float* __restrict__ s2,
    const float* __restrict__ d, short* __restrict__ wm)
{
    int idx = blockIdx.x * 256 + threadIdx.x;
    int ic  = idx & 127;
    int oc  = (idx >> 7) & 127;
    int t   = idx >> 14;            // cb*9+tap, < 288
    int tap = t % 9;
    int cb  = t / 9;                // conv*16+b
    int b   = cb & 15;
    int conv= cb >> 4;
    const float* w = conv ? w2 : w1;
    const float* s = conv ? s2 : s1;
    float v = w[(oc * C + ic) * 9 + tap] * (s[b * C + ic] + 1.0f)
            * d[(conv * B + b) * C + oc];
    int dst = cb * 147456
            + ((tap * 8 + (oc >> 4)) * 4 + (ic >> 5)) * 512
            + (oc & 15) * 32 + (ic & 31);
    wm[dst] = f2bs(v);
}

// ---------------------------------------------------------------------------
// dwexpand: dwm[tap][ocT=oc>>4 (16)][icC=ic>>5 (4)][(oc&15)*32+(ic&31)]
// ---------------------------------------------------------------------------
__global__ __launch_bounds__(256) void dwexpand_kernel(
    const float* __restrict__ dw, short* __restrict__ dwm)
{
    int idx = blockIdx.x * 256 + threadIdx.x;   // 16*256*128 = 524288
    int ic  = idx & 127;
    int oc  = (idx >> 7) & 255;
    int tap = idx >> 15;
    int dst = ((tap * 16 + (oc >> 4)) * 4 + (ic >> 5)) * 512
            + (oc & 15) * 32 + (ic & 31);
    dwm[dst] = f2bs(dw[(oc * C + ic) * 16 + tap]);
}

// ---------------------------------------------------------------------------
// nchw(f32) -> nhwc(bf16) transpose of features.
// ---------------------------------------------------------------------------
__global__ __launch_bounds__(256) void nchw2nhwc_kernel(
    const float* __restrict__ in, short* __restrict__ out)
{
    __shared__ short s[128 * 136];
    int bid = blockIdx.x;                   // b*128 + h
    int h = bid & 127, b = bid >> 7;
    int tid = threadIdx.x;
    for (int i = tid; i < 128 * 32; i += 256) {
        int w4 = i & 31, ic = i >> 5;
        float4 v = *(const float4*)&in[((b * C + ic) * H + h) * W + w4 * 4];
        s[(w4 * 4 + 0) * 136 + ic] = f2bs(v.x);
        s[(w4 * 4 + 1) * 136 + ic] = f2bs(v.y);
        s[(w4 * 4 + 2) * 136 + ic] = f2bs(v.z);
        s[(w4 * 4 + 3) * 136 + ic] = f2bs(v.w);
    }
    __syncthreads();
    for (int i = tid; i < 128 * 16; i += 256) {
        int icg = i & 15, w = i >> 4;
        *(uint4*)&out[((b * H + h) * W + w) * C + icg * 8] =
            *(uint4*)&s[w * 136 + icg * 8];
    }
}

// ---------------------------------------------------------------------------
// conv3x3 MFMA implicit GEMM.
// Round-6: XCD-aware block swizzle (T1). Evidence: r5 ring-2 NULL ->
// exposed latency ~650cy = L3, not L2. Cause: per-conv weight set 16b x
// 288KB = 4.6MB > 4MB per-XCD L2, and default blockIdx round-robins b's
// across XCDs so every XCD caches all 16 b's. Swizzle gives each XCD 256
// consecutive logical blocks = 2 b's = 576KB weights -> L2-resident.
// (2048 % 8 == 0 -> m157 swizzle bijective.)
// Keep: 36-step unrolled K loop, bf ring-3 (distance 2 now covers L2
// ~200cy), af distance-1, T5 setprio. Register math: 84 arch + 64 acc,
// 3 waves/SIMD at launch_bounds(256,3).
// ---------------------------------------------------------------------------
__global__ __launch_bounds__(256, 3) void conv3x3_mfma(
    const short* __restrict__ in, const short* __restrict__ wmc,
    const short* __restrict__ res, short* __restrict__ out)
{
    __shared__ short sIn[10 * 18 * 136];   // 48,960 B

    // T1: XCD-aware swizzle. xcd = hw_bid % 8; give each XCD a contiguous
    // 256-block chunk of the logical grid (= 2 batch images).
    int bid0 = blockIdx.x;
    int bid  = (bid0 & 7) * 256 + (bid0 >> 3);

    int wt = bid & 7, ht = (bid >> 3) & 15, b = bid >> 7;
    int w0 = wt * 16, h0 = ht * 8;
    int tid  = threadIdx.x;
    int lane = tid & 63, wv = tid >> 6;
    int q = lane >> 4, l15 = lane & 15;
    int wr = wv & 1;       // row half
    int wc = wv >> 1;      // oc half

    for (int i = tid; i < 10 * 18 * 16; i += 256) {
        int icg = i & 15;
        int t = i >> 4;
        int wl = t % 18, hl = t / 18;
        int gh = h0 - 1 + hl, gw = w0 - 1 + wl;
        uint4 v = make_uint4(0u, 0u, 0u, 0u);
        if ((unsigned)gh < (unsigned)H && (unsigned)gw < (unsigned)W)
            v = *(const uint4*)&in[((b * H + gh) * W + gw) * C + icg * 8];
        *(uint4*)&sIn[(hl * 18 + wl) * 136 + icg * 8] = v;
    }
    __syncthreads();

    const short* wb = wmc + b * 147456;

    f32x4 acc[4][4];
    #pragma unroll
    for (int mt = 0; mt < 4; ++mt)
        #pragma unroll
        for (int nt = 0; nt < 4; ++nt)
            acc[mt][nt] = (f32x4){0.f, 0.f, 0.f, 0.f};

    bf16x8 af[2][4];   // pixels (LDS), parity s&1, distance 1
    bf16x8 bf[3][4];   // weights (global), ring s%3, distance 2

    // K-step s = tap*4 + c  (tap = s>>2 since 36 = 9*4, c = s&3)
    auto ldAF = [&](int slot, int tap, int c) {
        int dh = tap / 3, dw = tap - dh * 3;
        #pragma unroll
        for (int mt = 0; mt < 4; ++mt)
            af[slot][mt] = *(const bf16x8*)&sIn[((wr * 4 + mt + dh) * 18 + l15 + dw) * 136
                                                + c * 32 + q * 8];
    };
    auto ldBF = [&](int slot, int tap, int c) {
        #pragma unroll
        for (int nt = 0; nt < 4; ++nt)
            bf[slot][nt] = *(const bf16x8*)&wb[((tap * 8 + wc * 4 + nt) * 4 + c) * 512
                                               + l15 * 32 + q * 8];
    };

    // prologue: af step 0; bf steps 0,1
    ldAF(0, 0, 0);
    ldBF(0, 0, 0);
    ldBF(1, 0, 1);

    #pragma unroll
    for (int s = 0; s < 36; ++s) {
        // issue global (long-latency) prefetch first: step s+2 into ring slot
        int s2 = (s + 2 < 36) ? s + 2 : s;       // dummy at tail
        ldBF((s + 2) % 3, s2 >> 2, s2 & 3);
        // LDS prefetch: step s+1
        int s1 = (s + 1 < 36) ? s + 1 : s;       // dummy at tail
        ldAF((s + 1) & 1, s1 >> 2, s1 & 3);
        // compute step s (T5: favor MFMA waves while others stage/load)
        __builtin_amdgcn_s_setprio(1);
        #pragma unroll
        for (int mt = 0; mt < 4; ++mt)
            #pragma unroll
            for (int nt = 0; nt < 4; ++nt)
                acc[mt][nt] = __builtin_amdgcn_mfma_f32_16x16x32_bf16(
                    af[s & 1][mt], bf[s % 3][nt], acc[mt][nt], 0, 0, 0);
        __builtin_amdgcn_s_setprio(0);
    }

    bool has_res = (res != nullptr);
    #pragma unroll
    for (int mt = 0; mt < 4; ++mt) {
        int h = h0 + wr * 4 + mt;
        #pragma unroll
        for (int nt = 0; nt < 4; ++nt) {
            int oc = wc * 64 + nt * 16 + l15;
            #pragma unroll
            for (int reg = 0; reg < 4; ++reg) {
                int w = w0 + q * 4 + reg;
                int idx = ((b * H + h) * W + w) * C + oc;
                float v = acc[mt][nt][reg];
                if (has_res) v += bs2f(res[idx]);
                v = v >= 0.f ? v : SLOPE * v;
                out[idx] = f2bs(v);
            }
        }
    }
}

// ---------------------------------------------------------------------------
// downconv MFMA — round-2 structure + T5 setprio (warm ~<144 us in r4).
//  - A (weights, global/L2): 4-slot register ring, prefetch 3 K-steps ahead.
//    (dwm = 1MB total, L2-fits on every XCD -> no swizzle needed here.)
//  - Input staging: direct barrier-bracketed stage per ic-chunk.
//  LESSONS (do not regress):
//   r1: +pre[11] T14 staging -> >128 arch VGPR -> scratch spill (WRITE 488MB).
//   r3: 4oh-tile/double-buffer/1-barrier restructure -> FETCH 373MB, 333us.
//   r4: T5 setprio around MFMA cluster: 191 -> <144 us. Keep.
// ---------------------------------------------------------------------------
__global__ __launch_bounds__(256, 2) void downconv_mfma(
    const short* __restrict__ in, const short* __restrict__ dwm,
    const float* __restrict__ db, float* __restrict__ out)
{
    __shared__ short sIn[19 * 2 * 18 * 40];   // 54,720 B

    int bid = blockIdx.x;
    int wt = bid & 3;  bid >>= 2;
    int ht = bid & 7;  bid >>= 3;
    int ot = bid & 1;  bid >>= 1;
    int b  = bid;
    int ow0 = wt * 16, oh0 = ht * 8, oc0 = ot * 128;

    int tid  = threadIdx.x;
    int lane = tid & 63, wv = tid >> 6;
    int q = lane >> 4, l15 = lane & 15;
    int wo = wv & 1;
    int wp = wv >> 1;

    f32x4 acc[4][4];
    #pragma unroll
    for (int mt = 0; mt < 4; ++mt)
        #pragma unroll
        for (int nt = 0; nt < 4; ++nt)
            acc[mt][nt] = (f32x4){0.f, 0.f, 0.f, 0.f};

    int ocTb = ot * 8 + wo * 4;   // this wave's oc-tile base (16-oc units)

    // ---- direct stage of ic-chunk 0 ----
    for (int i = tid; i < 19 * 35 * 4; i += 256) {
        int icg = i & 3;
        int t = i >> 2;
        int wl = t % 35, hl = t / 35;
        int gh = 2 * oh0 - 1 + hl, gw = 2 * ow0 - 1 + wl;
        uint4 v = make_uint4(0u, 0u, 0u, 0u);
        if ((unsigned)gh < (unsigned)H && (unsigned)gw < (unsigned)W)
            v = *(const uint4*)&in[((b * H + gh) * W + gw) * C + icg * 8];
        *(uint4*)&sIn[((hl * 2 + (wl & 1)) * 18 + (wl >> 1)) * 40 + icg * 8] = v;
    }

    bf16x8 af[4][4];   // A ring: slot = (c*16+tap) & 3, filled 3 steps ahead
    bf16x8 bf[2][4];   // B parity: slot = tap & 1

    // A-pipeline prologue: steps 0..2 (c=0, taps 0..2) — no LDS dependence
    #pragma unroll
    for (int s = 0; s < 3; ++s)
        #pragma unroll
        for (int mt = 0; mt < 4; ++mt)
            af[s][mt] = *(const bf16x8*)&dwm[((s * 16 + ocTb + mt) * 4 + 0) * 512
                                             + l15 * 32 + q * 8];

    __syncthreads();

    #pragma unroll 1
    for (int c = 0; c < 4; ++c) {
        // B prologue: tap 0 (dh=0, dw=0)
        #pragma unroll
        for (int nt = 0; nt < 4; ++nt) {
            int hl = 2 * (wp * 4 + nt);
            bf[0][nt] = *(const bf16x8*)&sIn[(hl * 2 * 18 + l15) * 40 + q * 8];
        }

        #pragma unroll
        for (int tap = 0; tap < 16; ++tap) {
            // A prefetch: flattened step s+3 (crosses the c boundary)
            {
                int sp = c * 16 + tap + 3;
                sp = sp < 63 ? sp : 63;          // dummy tail prefetch
                int pc = sp >> 4, pt = sp & 15;
                #pragma unroll
                for (int mt = 0; mt < 4; ++mt)
                    af[(tap + 3) & 3][mt] =
                        *(const bf16x8*)&dwm[((pt * 16 + ocTb + mt) * 4 + pc) * 512
                                             + l15 * 32 + q * 8];
            }
            // B prefetch: tap+1
            {
                int tapn = (tap + 1 < 16) ? tap + 1 : tap;
                int dhn = tapn >> 2, dwn = tapn & 3;
                #pragma unroll
                for (int nt = 0; nt < 4; ++nt) {
                    int hl = 2 * (wp * 4 + nt) + dhn;
                    bf[(tap + 1) & 1][nt] =
                        *(const bf16x8*)&sIn[((hl * 2 + (dwn & 1)) * 18 + l15 + (dwn >> 1)) * 40
                                             + q * 8];
                }
            }
            // compute tap (T5)
            __builtin_amdgcn_s_setprio(1);
            #pragma unroll
            for (int mt = 0; mt < 4; ++mt)
                #pragma unroll
                for (int nt = 0; nt < 4; ++nt)
                    acc[mt][nt] = __builtin_amdgcn_mfma_f32_16x16x32_bf16(
                        af[tap & 3][mt], bf[tap & 1][nt], acc[mt][nt], 0, 0, 0);
            __builtin_amdgcn_s_setprio(0);
        }

        if (c < 3) {
            __syncthreads();                     // all reads of chunk c done
            for (int i = tid; i < 19 * 35 * 4; i += 256) {
                int icg = i & 3;
                int t = i >> 2;
                int wl = t % 35, hl = t / 35;
                int gh = 2 * oh0 - 1 + hl, gw = 2 * ow0 - 1 + wl;
                uint4 v = make_uint4(0u, 0u, 0u, 0u);
                if ((unsigned)gh < (unsigned)H && (unsigned)gw < (unsigned)W)
                    v = *(const uint4*)&in[((b * H + gh) * W + gw) * C
                                           + (c + 1) * 32 + icg * 8];
                *(uint4*)&sIn[((hl * 2 + (wl & 1)) * 18 + (wl >> 1)) * 40 + icg * 8] = v;
            }
            __syncthreads();                     // chunk c+1 visible
        }
    }

    #pragma unroll
    for (int mt = 0; mt < 4; ++mt) {
        #pragma unroll
        for (int reg = 0; reg < 4; ++reg) {
            int oc = oc0 + wo * 64 + mt * 16 + q * 4 + reg;
            float bias = db[oc];
            #pragma unroll
            for (int nt = 0; nt < 4; ++nt) {
                int oh = oh0 + wp * 4 + nt;
                int ow = ow0 + l15;
                out[((b * CO + oc) * HO + oh) * WO + ow] = acc[mt][nt][reg] + bias;
            }
        }
    }
}

// ---------------------------------------------------------------------------
extern "C" void kernel_launch(void* const* d_in, const int* in_sizes, int n_in,
                              void* d_out, int out_size, void* d_ws, size_t ws_size,
                              hipStream_t stream) {
    const float* features = (const float*)d_in[0];
    const float* sm1      = (const float*)d_in[1];   // style_mean1 -> s1
    const float* ss1      = (const float*)d_in[2];   // style_std1  -> s2 (per reference)
    const float* w1       = (const float*)d_in[6];
    const float* w2       = (const float*)d_in[7];
    const float* dw       = (const float*)d_in[8];
    const float* db       = (const float*)d_in[9];
    float* out = (float*)d_out;

    char* ws = (char*)d_ws;
    short* x1  = (short*)ws;                              // 67,108,864 B
    short* x2  = (short*)(ws + 67108864);                 // 67,108,864 B (also fx)
    short* wm  = (short*)(ws + 134217728);                // 9,437,184 B
    short* dwm = (short*)(ws + 143654912);                // 1,048,576 B
    float* dv  = (float*)(ws + 144703488);                // 16,384 B

    demod_kernel    <<<4096, 128, 0, stream>>>(w1, w2, sm1, ss1, dv);
    expand_kernel   <<<18432, 256, 0, stream>>>(w1, w2, sm1, ss1, dv, wm);
    dwexpand_kernel <<<2048, 256, 0, stream>>>(dw, dwm);
    nchw2nhwc_kernel<<<2048, 256, 0, stream>>>(features, x2);
    conv3x3_mfma    <<<2048, 256, 0, stream>>>(x2, wm, nullptr, x1);
    conv3x3_mfma    <<<2048, 256, 0, stream>>>(x1, wm + 16 * 147456, x1, x2);
    downconv_mfma   <<<1024, 256, 0, stream>>>(x2, dwm, db, out);
}